// Round 2
// baseline (259.675 us; speedup 1.0000x reference)
//
#include <hip/hip_runtime.h>

// x [B=16, N=1024, F=256] fp32.  Algebra (alpha folded away):
//   Wab = Wa^T @ Wb  (prep, bf16)          Wcb = bf16(Wr@Wu); bc = Wr@bu
//   ab  = x @ Wab^T   (P1)                 U2 = x @ Wcb^T + bc
//   d[m] = x[m]·ab[m] (diag term; == alpha[m]·beta[m])
//   G[b][j][f] = sum_i U2[b,i,j] * ab[b,i,f]      (F x F per batch, P2 NT)
//   out[m,j] = (x[m,:]·G[b][j,:] - d[m]*U2[m,j]) / N + x[m,j]   (P3 NT)
// Single persistent mega-kernel: P1 -> gridbar -> P2 -> gridbar -> P3.
// 512 blocks x 256 thr, __launch_bounds__(256,2) => >=2 blocks/CU co-resident
// (capacity 512 >= grid 512), so the atomic-counter grid barrier cannot deadlock.

typedef __bf16 bf16;
typedef float floatx4 __attribute__((ext_vector_type(4)));
typedef bf16 bf16x8 __attribute__((ext_vector_type(8)));
typedef bf16 bf16x4 __attribute__((ext_vector_type(4)));

constexpr int FD = 256;
constexpr int NB = 16;
constexpr int NN = 1024;
constexpr int RR = NB * NN;   // 16384

__device__ __forceinline__ bf16x8 cvt8(float4 a, float4 b) {
    bf16x8 o = { (bf16)a.x, (bf16)a.y, (bf16)a.z, (bf16)a.w,
                 (bf16)b.x, (bf16)b.y, (bf16)b.z, (bf16)b.w };
    return o;
}

// ---- LDS union across phases (max 36352 B) ----
struct P1s { bf16 As[128][36]; bf16 Bs[2][64][36]; bf16 Tr[8960]; }; // 9216+9216+17920
struct P2s { bf16 As[64][72];  bf16 Bs[32][72];    bf16 Tr[64*36]; }; // 9216+4608+4608
struct P3s { bf16 As[128][36]; bf16 Bs[64][36]; };                    // 9216+4608
union SMem { P1s p1; P2s p2; P3s p3; };

// ---- grid barrier: release-fence + device-scope atomic arrive + acquire spin ----
__device__ __forceinline__ void grid_barrier(int* cnt, int target) {
    __syncthreads();
    if (threadIdx.x == 0) {
        __threadfence();   // agent-scope release (L2 writeback for cross-XCD visibility)
        __hip_atomic_fetch_add(cnt, 1, __ATOMIC_ACQ_REL, __HIP_MEMORY_SCOPE_AGENT);
        while (__hip_atomic_load(cnt, __ATOMIC_ACQUIRE, __HIP_MEMORY_SCOPE_AGENT) < target)
            __builtin_amdgcn_s_sleep(2);
    }
    __syncthreads();
}

// ---------------- K1: prep (separate launch; also zeroes barrier counter) ----------------
__global__ __launch_bounds__(256)
void prep(const float* __restrict__ Wa, const float* __restrict__ Wb,
          const float* __restrict__ Wu, const float* __restrict__ bu,
          const float* __restrict__ Wr,
          bf16* __restrict__ Wcb, bf16* __restrict__ Wab, float* __restrict__ bc,
          int* __restrict__ cnt)
{
    const int blk = blockIdx.x, tid = threadIdx.x;
    if (blk < 256) {  // Wcb[j][f] = sum_g Wr[j][g]*Wu[g][f]; one j per block
        const int j = blk;
        float acc = 0.0f;
        for (int g = 0; g < FD; g += 4) {
            float4 wr = *(const float4*)&Wr[j * FD + g];
            acc += wr.x * Wu[g * FD + tid] + wr.y * Wu[(g + 1) * FD + tid]
                 + wr.z * Wu[(g + 2) * FD + tid] + wr.w * Wu[(g + 3) * FD + tid];
        }
        Wcb[j * FD + tid] = (bf16)acc;
    } else if (blk == 256) {  // bc[j] = Wr[j,:].bu  (+ zero the grid-barrier counter)
        if (tid == 0) *cnt = 0;
        float s = 0.0f;
        for (int g = 0; g < FD; g++) s += Wr[tid * FD + g] * bu[g];
        bc[tid] = s;
    } else {  // Wab[f][g] = sum_k Wa[k][f]*Wb[k][g]; one f per block
        const int f = blk - 257;
        float acc = 0.0f;
        for (int k = 0; k < FD; k += 4) {
            acc += Wa[k * FD + f] * Wb[k * FD + tid]
                 + Wa[(k + 1) * FD + f] * Wb[(k + 1) * FD + tid]
                 + Wa[(k + 2) * FD + f] * Wb[(k + 2) * FD + tid]
                 + Wa[(k + 3) * FD + f] * Wb[(k + 3) * FD + tid];
        }
        Wab[f * FD + tid] = (bf16)acc;
    }
}

// ---------------- P1: proj tile (BM=128 rows x BN=64 cols) ----------------
__device__ void proj_tile(int bx, int by, P1s& s,
                          const float* __restrict__ x,
                          const bf16* __restrict__ Wab, const bf16* __restrict__ Wc,
                          bf16* __restrict__ U2, bf16* __restrict__ abT, bf16* __restrict__ U2T,
                          const float* __restrict__ bc, float* __restrict__ dpart)
{
    constexpr int BK = 32;
    const int tid = threadIdx.x;
    const int wave = tid >> 6, lane = tid & 63;
    const int q = lane >> 4, l16 = lane & 15;
    const int bm = by * 128, bn = bx * 64;

    const int rowA0 = tid >> 2,          k8A0 = (tid & 3) * 8;
    const int rowA1 = (tid + 256) >> 2,  k8A1 = (tid & 3) * 8;
    const int rowW  = tid >> 2,          k8W  = (tid & 3) * 8;

    bf16x8 pxa0, pxa1; int4 pwq, pwc;
#define PROJ_LOAD(KK) do { \
        const float* s0 = &x[(size_t)(bm + rowA0) * FD + (KK) + k8A0]; \
        pxa0 = cvt8(*(const float4*)s0, *(const float4*)(s0 + 4)); \
        const float* s1 = &x[(size_t)(bm + rowA1) * FD + (KK) + k8A1]; \
        pxa1 = cvt8(*(const float4*)s1, *(const float4*)(s1 + 4)); \
        pwq = *(const int4*)&Wab[(size_t)(bn + rowW) * FD + (KK) + k8W]; \
        pwc = *(const int4*)&Wc[(size_t)(bn + rowW) * FD + (KK) + k8W]; \
    } while (0)

    floatx4 acc[2][2][4] = {};   // [0]=ab, [1]=U2
    PROJ_LOAD(0);

    for (int k0 = 0; k0 < FD; k0 += BK) {
        *(bf16x8*)&s.As[rowA0][k8A0] = pxa0;
        *(bf16x8*)&s.As[rowA1][k8A1] = pxa1;
        *(int4*)&s.Bs[0][rowW][k8W] = pwq;
        *(int4*)&s.Bs[1][rowW][k8W] = pwc;
        __syncthreads();
        if (k0 + BK < FD) PROJ_LOAD(k0 + BK);
        bf16x8 af[2];
        #pragma unroll
        for (int mi = 0; mi < 2; mi++)
            af[mi] = *(const bf16x8*)&s.As[wave * 32 + mi * 16 + l16][q * 8];
        #pragma unroll
        for (int w = 0; w < 2; w++) {
            bf16x8 bq[4];
            #pragma unroll
            for (int nj = 0; nj < 4; nj++)
                bq[nj] = *(const bf16x8*)&s.Bs[w][nj * 16 + l16][q * 8];
            #pragma unroll
            for (int mi = 0; mi < 2; mi++)
                #pragma unroll
                for (int nj = 0; nj < 4; nj++)
                    acc[w][mi][nj] = __builtin_amdgcn_mfma_f32_16x16x32_bf16(af[mi], bq[nj], acc[w][mi][nj], 0, 0, 0);
        }
        __syncthreads();
    }
#undef PROJ_LOAD

    const int b = bm >> 10, n0 = bm & (NN - 1);
    float bcv[4];
    #pragma unroll
    for (int nj = 0; nj < 4; nj++) bcv[nj] = bc[bn + nj * 16 + l16];

    // diag partials: d[m] (this tile's 64 f-cols) = sum_f x[m,f]*ab[m,f]
    #pragma unroll
    for (int mi = 0; mi < 2; mi++)
        #pragma unroll
        for (int i = 0; i < 4; i++) {
            const int m = bm + wave * 32 + mi * 16 + q * 4 + i;
            float p = 0.0f;
            #pragma unroll
            for (int nj = 0; nj < 4; nj++)
                p += x[(size_t)m * FD + bn + nj * 16 + l16] * acc[0][mi][nj][i];
            #pragma unroll
            for (int off = 1; off < 16; off <<= 1) p += __shfl_xor(p, off);
            if (l16 == 0) dpart[(size_t)bx * RR + m] = p;
        }

    // natural output via [128][68] repack: U2 (+bc)
    __syncthreads();
    #pragma unroll
    for (int mi = 0; mi < 2; mi++)
        #pragma unroll
        for (int i = 0; i < 4; i++) {
            int ml = wave * 32 + mi * 16 + q * 4 + i;
            #pragma unroll
            for (int nj = 0; nj < 4; nj++)
                s.Tr[ml * 68 + nj * 16 + l16] = (bf16)(acc[1][mi][nj][i] + bcv[nj]);
        }
    __syncthreads();
    #pragma unroll
    for (int it = 0; it < 4; it++) {
        int c = tid + it * 256;
        int row = c >> 3, chunk = c & 7;
        bf16x8 v = *(const bf16x8*)&s.Tr[row * 68 + chunk * 8];
        *(bf16x8*)&U2[(size_t)(bm + row) * FD + bn + chunk * 8] = v;
    }

    // transposed outputs via [64][140] repack: abT (pass 0), U2T (pass 1, +bc)
    #pragma unroll
    for (int pass = 0; pass < 2; pass++) {
        __syncthreads();
        #pragma unroll
        for (int mi = 0; mi < 2; mi++)
            #pragma unroll
            for (int nj = 0; nj < 4; nj++) {
                bf16x4 v4;
                #pragma unroll
                for (int i = 0; i < 4; i++) {
                    float v = acc[pass][mi][nj][i];
                    if (pass == 1) v += bcv[nj];
                    v4[i] = (bf16)v;
                }
                *(bf16x4*)&s.Tr[(nj * 16 + l16) * 140 + wave * 32 + mi * 16 + q * 4] = v4;
            }
        __syncthreads();
        bf16* dst = (pass ? U2T : abT) + (size_t)b * FD * NN;
        #pragma unroll
        for (int it = 0; it < 4; it++) {
            int c = tid + it * 256;
            int row = c >> 4, chunk = c & 15;
            bf16x8 v = *(const bf16x8*)&s.Tr[row * 140 + chunk * 8];
            *(bf16x8*)&dst[(size_t)(bn + row) * NN + n0 + chunk * 8] = v;
        }
    }
}

// ---------------- P2: G tile 64(j) x 32(k), K=1024, BK=64.  512 tiles: 8(bk) x 4(bj) x 16(b) ----------------
__device__ void m2_tile(int bkt, int bjt, int b, P2s& s,
                        const bf16* __restrict__ U2T, const bf16* __restrict__ abT,
                        bf16* __restrict__ G)
{
    const int tid = threadIdx.x;
    const int wave = tid >> 6, lane = tid & 63;
    const int q = lane >> 4, l16 = lane & 15;
    const int bj = bjt * 64, bk = bkt * 32;
    const int rA0 = tid >> 3, rA1 = rA0 + 32, k8 = (tid & 7) * 8;
    const bf16* Arow0 = U2T + (size_t)b * FD * NN + (size_t)(bj + rA0) * NN + k8;
    const bf16* Arow1 = U2T + (size_t)b * FD * NN + (size_t)(bj + rA1) * NN + k8;
    const bf16* Brow  = abT + (size_t)b * FD * NN + (size_t)(bk + rA0) * NN + k8;

    int4 ra0 = *(const int4*)&Arow0[0];
    int4 ra1 = *(const int4*)&Arow1[0];
    int4 rb  = *(const int4*)&Brow[0];
    floatx4 acc[2] = {};
    for (int n0 = 0; n0 < NN; n0 += 64) {
        *(int4*)&s.As[rA0][k8] = ra0;
        *(int4*)&s.As[rA1][k8] = ra1;
        *(int4*)&s.Bs[rA0][k8] = rb;
        __syncthreads();
        if (n0 + 64 < NN) {
            ra0 = *(const int4*)&Arow0[n0 + 64];
            ra1 = *(const int4*)&Arow1[n0 + 64];
            rb  = *(const int4*)&Brow[n0 + 64];
        }
        #pragma unroll
        for (int kk = 0; kk < 2; kk++) {
            bf16x8 af = *(const bf16x8*)&s.As[wave * 16 + l16][kk * 32 + q * 8];
            #pragma unroll
            for (int kj = 0; kj < 2; kj++) {
                bf16x8 bq = *(const bf16x8*)&s.Bs[kj * 16 + l16][kk * 32 + q * 8];
                acc[kj] = __builtin_amdgcn_mfma_f32_16x16x32_bf16(af, bq, acc[kj], 0, 0, 0);
            }
        }
        __syncthreads();
    }
    // repack [64][36] then b128 stores
    __syncthreads();
    #pragma unroll
    for (int i = 0; i < 4; i++) {
        int jl = wave * 16 + q * 4 + i;
        #pragma unroll
        for (int kj = 0; kj < 2; kj++)
            s.Tr[jl * 36 + kj * 16 + l16] = (bf16)acc[kj][i];
    }
    __syncthreads();
    bf16* Gb = G + (size_t)b * FD * FD;
    {
        int r = tid >> 2, chunk = tid & 3;
        bf16x8 v = *(const bf16x8*)&s.Tr[r * 36 + chunk * 8];
        *(bf16x8*)&Gb[(size_t)(bj + r) * FD + bk + chunk * 8] = v;
    }
}

// ---------------- P3: out = (x_bf @ G[b]^T(NT) - d*U2)/N + x ----------------
__device__ void final_tile(int bx, int by, P3s& s,
                           const float* __restrict__ x, const bf16* __restrict__ G,
                           const float* __restrict__ dpart, const bf16* __restrict__ U2,
                           float* __restrict__ out)
{
    constexpr int BK = 32;
    const int tid = threadIdx.x;
    const int wave = tid >> 6, lane = tid & 63;
    const int q = lane >> 4, l16 = lane & 15;
    const int bm = by * 128, bn = bx * 64;
    const bf16* Gb = G + (size_t)(bm >> 10) * FD * FD;

    const int rowA0 = tid >> 2,         k8A0 = (tid & 3) * 8;
    const int rowA1 = (tid + 256) >> 2, k8A1 = (tid & 3) * 8;
    const int rowB  = tid >> 2,         k8B  = (tid & 3) * 8;

    bf16x8 ra0, ra1; int4 rb;
#define FIN_LOAD(KK) do { \
        const float* s0 = &x[(size_t)(bm + rowA0) * FD + (KK) + k8A0]; \
        ra0 = cvt8(*(const float4*)s0, *(const float4*)(s0 + 4)); \
        const float* s1 = &x[(size_t)(bm + rowA1) * FD + (KK) + k8A1]; \
        ra1 = cvt8(*(const float4*)s1, *(const float4*)(s1 + 4)); \
        rb = *(const int4*)&Gb[(size_t)(bn + rowB) * FD + (KK) + k8B]; \
    } while (0)

    floatx4 acc[2][4] = {};
    FIN_LOAD(0);
    for (int k0 = 0; k0 < FD; k0 += BK) {
        *(bf16x8*)&s.As[rowA0][k8A0] = ra0;
        *(bf16x8*)&s.As[rowA1][k8A1] = ra1;
        *(int4*)&s.Bs[rowB][k8B] = rb;
        __syncthreads();
        if (k0 + BK < FD) FIN_LOAD(k0 + BK);
        bf16x8 af[2], bq[4];
        #pragma unroll
        for (int mi = 0; mi < 2; mi++)
            af[mi] = *(const bf16x8*)&s.As[wave * 32 + mi * 16 + l16][q * 8];
        #pragma unroll
        for (int nj = 0; nj < 4; nj++)
            bq[nj] = *(const bf16x8*)&s.Bs[nj * 16 + l16][q * 8];
        #pragma unroll
        for (int mi = 0; mi < 2; mi++)
            #pragma unroll
            for (int nj = 0; nj < 4; nj++)
                acc[mi][nj] = __builtin_amdgcn_mfma_f32_16x16x32_bf16(af[mi], bq[nj], acc[mi][nj], 0, 0, 0);
        __syncthreads();
    }
#undef FIN_LOAD

    #pragma unroll
    for (int mi = 0; mi < 2; mi++)
        #pragma unroll
        for (int i = 0; i < 4; i++) {
            int m = bm + wave * 32 + mi * 16 + q * 4 + i;
            float d = dpart[m] + dpart[RR + m] + dpart[2 * RR + m] + dpart[3 * RR + m];
            #pragma unroll
            for (int nj = 0; nj < 4; nj++) {
                int n = bn + nj * 16 + l16;
                float v = (acc[mi][nj][i] - d * (float)U2[(size_t)m * FD + n]) * (1.0f / 1024.0f);
                out[(size_t)m * FD + n] = v + x[(size_t)m * FD + n];
            }
        }
}

// ---------------- mega: P1 -> bar -> P2 -> bar -> P3 ----------------
__global__ __launch_bounds__(256, 2)
void mega(const float* __restrict__ x,
          const bf16* __restrict__ Wab, const bf16* __restrict__ Wcb,
          const float* __restrict__ bc,
          bf16* __restrict__ U2, bf16* __restrict__ abT, bf16* __restrict__ U2T,
          bf16* __restrict__ G, float* __restrict__ dpart,
          float* __restrict__ out, int* __restrict__ cnt)
{
    __shared__ SMem sm;
    const int bid = blockIdx.x;

    // P1: 512 tiles, 1:1
    proj_tile(bid & 3, bid >> 2, sm.p1, x, Wab, Wcb, U2, abT, U2T, bc, dpart);

    grid_barrier(cnt, 512);

    // P2: 512 tiles, 1:1  (8 bk x 4 bj x 16 b)
    m2_tile(bid & 7, (bid >> 3) & 3, bid >> 5, sm.p2, U2T, abT, G);

    grid_barrier(cnt, 1024);

    // P3: 512 tiles, 1:1
    final_tile(bid & 3, bid >> 2, sm.p3, x, G, dpart, U2, out);
}

extern "C" void kernel_launch(void* const* d_in, const int* in_sizes, int n_in,
                              void* d_out, int out_size, void* d_ws, size_t ws_size,
                              hipStream_t stream)
{
    const float* x  = (const float*)d_in[0];
    const float* Wa = (const float*)d_in[1];
    const float* Wb = (const float*)d_in[2];
    const float* Wu = (const float*)d_in[3];
    const float* bu = (const float*)d_in[4];
    const float* Wr = (const float*)d_in[5];
    float* out = (float*)d_out;

    char* w = (char*)d_ws;
    bf16* Wcb   = (bf16*)w;  w += (size_t)FD * FD * 2;
    bf16* Wab   = (bf16*)w;  w += (size_t)FD * FD * 2;
    float* bc   = (float*)w; w += (size_t)FD * 4;
    bf16* U2    = (bf16*)w;  w += (size_t)RR * FD * 2;
    bf16* abT   = (bf16*)w;  w += (size_t)RR * FD * 2;
    bf16* U2T   = (bf16*)w;  w += (size_t)RR * FD * 2;
    bf16* G     = (bf16*)w;  w += (size_t)NB * FD * FD * 2;
    float* dpart= (float*)w; w += (size_t)4 * RR * 4;
    int* cnt    = (int*)w;   w += 256;

    dim3 blk(256);

    prep<<<dim3(513), blk, 0, stream>>>(Wa, Wb, Wu, bu, Wr, Wcb, Wab, bc, cnt);

    mega<<<dim3(512), blk, 0, stream>>>(x, Wab, Wcb, bc, U2, abT, U2T, G, dpart, out, cnt);
}

// Round 3
// 176.594 us; speedup vs baseline: 1.4705x; 1.4705x over previous
//
#include <hip/hip_runtime.h>

// x [B=16, N=1024, F=256] fp32.  Algebra (alpha folded away):
//   Wab = Wa^T @ Wb  (prep, bf16)          Wcb = bf16(Wr@Wu); bc = Wr@bu
//   ab  = x @ Wab^T   (proj)               U2 = x @ Wcb^T + bc
//   d[m] = x[m]·ab[m] (diag term; == alpha[m]·beta[m])
//   G[b][j][f] = sum_i U2[b,i,j] * ab[b,i,f]      (F x F per batch, split-K fp32 halves)
//   out[m,j] = (x[m,:]·G[b][j,:] - d[m]*U2[m,j]) / N + x[m,j]
// Round-3 retile for latency-hiding (counters showed 2% MFMA / 2% VALU / 12% HBM):
//   proj/final BM=64 -> 1024 blocks (4/CU), m2 split-K -> 512 blocks (2/CU),
//   double-buffered LDS (1 sync per K-step), launch_bounds(256,4).

typedef __bf16 bf16;
typedef float floatx4 __attribute__((ext_vector_type(4)));
typedef bf16 bf16x8 __attribute__((ext_vector_type(8)));
typedef bf16 bf16x4 __attribute__((ext_vector_type(4)));

constexpr int FD = 256;
constexpr int NB = 16;
constexpr int NN = 1024;
constexpr int RR = NB * NN;   // 16384
constexpr int GH = NB * FD * FD;  // one split-K half of G (fp32 elems)

__device__ __forceinline__ bf16x8 cvt8(float4 a, float4 b) {
    bf16x8 o = { (bf16)a.x, (bf16)a.y, (bf16)a.z, (bf16)a.w,
                 (bf16)b.x, (bf16)b.y, (bf16)b.z, (bf16)b.w };
    return o;
}

// ---------------- K1: prep ----------------
__global__ __launch_bounds__(256)
void prep(const float* __restrict__ Wa, const float* __restrict__ Wb,
          const float* __restrict__ Wu, const float* __restrict__ bu,
          const float* __restrict__ Wr,
          bf16* __restrict__ Wcb, bf16* __restrict__ Wab, float* __restrict__ bc)
{
    const int blk = blockIdx.x, tid = threadIdx.x;
    if (blk < 256) {  // Wcb[j][f] = sum_g Wr[j][g]*Wu[g][f]; one j per block
        const int j = blk;
        float acc = 0.0f;
        for (int g = 0; g < FD; g += 4) {
            float4 wr = *(const float4*)&Wr[j * FD + g];
            acc += wr.x * Wu[g * FD + tid] + wr.y * Wu[(g + 1) * FD + tid]
                 + wr.z * Wu[(g + 2) * FD + tid] + wr.w * Wu[(g + 3) * FD + tid];
        }
        Wcb[j * FD + tid] = (bf16)acc;
    } else if (blk == 256) {  // bc[j] = Wr[j,:].bu
        float s = 0.0f;
        for (int g = 0; g < FD; g++) s += Wr[tid * FD + g] * bu[g];
        bc[tid] = s;
    } else {  // Wab[f][g] = sum_k Wa[k][f]*Wb[k][g]; one f per block
        const int f = blk - 257;
        float acc = 0.0f;
        for (int k = 0; k < FD; k += 4) {
            acc += Wa[k * FD + f] * Wb[k * FD + tid]
                 + Wa[(k + 1) * FD + f] * Wb[(k + 1) * FD + tid]
                 + Wa[(k + 2) * FD + f] * Wb[(k + 2) * FD + tid]
                 + Wa[(k + 3) * FD + f] * Wb[(k + 3) * FD + tid];
        }
        Wab[f * FD + tid] = (bf16)acc;
    }
}

// ---------------- K2: proj (BM=64, BN=64, BK=32, dbuf) ----------------
__global__ __launch_bounds__(256, 4)
void proj(const float* __restrict__ x,
          const bf16* __restrict__ Wab, const bf16* __restrict__ Wc,
          bf16* __restrict__ U2, bf16* __restrict__ abT, bf16* __restrict__ U2T,
          const float* __restrict__ bc, float* __restrict__ dpart)
{
    // LDS: As[2][64][36] (9216 B) + Bs[2][2][64][36] (18432 B) = 27648 B; Tr aliases As.
    __shared__ __align__(16) bf16 smem[13824];
    typedef bf16 TileA[64][36];
    typedef bf16 TileB[2][64][36];
    TileA* As = (TileA*)smem;             // As[buf][row][k]
    TileB* Bs = (TileB*)(smem + 4608);    // Bs[buf][plane][row][k]
    bf16*  Tr = smem;                     // epilogue union [64][72]

    const int tid = threadIdx.x;
    const int wave = tid >> 6, lane = tid & 63;
    const int q = lane >> 4, l16 = lane & 15;
    const int bm = blockIdx.y * 64, bn = blockIdx.x * 64;

    const int row = tid >> 2, k8 = (tid & 3) * 8;   // 64 rows x 32 cols staging

    bf16x8 pxa; int4 pwq, pwc;
#define PROJ_LOAD(KK) do { \
        const float* s0 = &x[(size_t)(bm + row) * FD + (KK) + k8]; \
        pxa = cvt8(*(const float4*)s0, *(const float4*)(s0 + 4)); \
        pwq = *(const int4*)&Wab[(size_t)(bn + row) * FD + (KK) + k8]; \
        pwc = *(const int4*)&Wc[(size_t)(bn + row) * FD + (KK) + k8]; \
    } while (0)
#define PROJ_STORE(BUF) do { \
        *(bf16x8*)&As[BUF][row][k8] = pxa; \
        *(int4*)&Bs[BUF][0][row][k8] = pwq; \
        *(int4*)&Bs[BUF][1][row][k8] = pwc; \
    } while (0)

    floatx4 acc[2][4] = {};   // [plane][nj]; plane0=ab, plane1=U2
    PROJ_LOAD(0);
    PROJ_STORE(0);
    PROJ_LOAD(32);
    __syncthreads();

    #pragma unroll
    for (int it = 0; it < 8; it++) {
        const int cur = it & 1;
        if (it + 1 < 8) PROJ_STORE(cur ^ 1);
        if (it + 2 < 8) PROJ_LOAD((it + 2) * 32);
        bf16x8 af = *(const bf16x8*)&As[cur][wave * 16 + l16][q * 8];
        #pragma unroll
        for (int w = 0; w < 2; w++) {
            #pragma unroll
            for (int nj = 0; nj < 4; nj++) {
                bf16x8 bq = *(const bf16x8*)&Bs[cur][w][nj * 16 + l16][q * 8];
                acc[w][nj] = __builtin_amdgcn_mfma_f32_16x16x32_bf16(af, bq, acc[w][nj], 0, 0, 0);
            }
        }
        __syncthreads();
    }
#undef PROJ_LOAD
#undef PROJ_STORE

    const int b = bm >> 10, n0 = bm & (NN - 1);
    float bcv[4];
    #pragma unroll
    for (int nj = 0; nj < 4; nj++) bcv[nj] = bc[bn + nj * 16 + l16];

    // diag partials: d[m] (this tile's 64 f-cols) = sum_f x[m,f]*ab[m,f]
    #pragma unroll
    for (int i = 0; i < 4; i++) {
        const int m = bm + wave * 16 + q * 4 + i;
        float p = 0.0f;
        #pragma unroll
        for (int nj = 0; nj < 4; nj++)
            p += x[(size_t)m * FD + bn + nj * 16 + l16] * acc[0][nj][i];
        #pragma unroll
        for (int off = 1; off < 16; off <<= 1) p += __shfl_xor(p, off);
        if (l16 == 0) dpart[(size_t)blockIdx.x * RR + m] = p;
    }

    // natural output via Tr[64][72]: U2 (+bc)
    #pragma unroll
    for (int i = 0; i < 4; i++) {
        int ml = wave * 16 + q * 4 + i;
        #pragma unroll
        for (int nj = 0; nj < 4; nj++)
            Tr[ml * 72 + nj * 16 + l16] = (bf16)(acc[1][nj][i] + bcv[nj]);
    }
    __syncthreads();
    #pragma unroll
    for (int it = 0; it < 2; it++) {
        int c = tid + it * 256;
        int r = c >> 3, chunk = c & 7;
        bf16x8 v = *(const bf16x8*)&Tr[r * 72 + chunk * 8];
        *(bf16x8*)&U2[(size_t)(bm + r) * FD + bn + chunk * 8] = v;
    }

    // transposed outputs via Tr[64][72]: abT (pass 0), U2T (pass 1, +bc)
    #pragma unroll
    for (int pass = 0; pass < 2; pass++) {
        __syncthreads();
        #pragma unroll
        for (int nj = 0; nj < 4; nj++) {
            bf16x4 v4;
            #pragma unroll
            for (int i = 0; i < 4; i++) {
                float v = acc[pass][nj][i];
                if (pass == 1) v += bcv[nj];
                v4[i] = (bf16)v;
            }
            *(bf16x4*)&Tr[(nj * 16 + l16) * 72 + wave * 16 + q * 4] = v4;
        }
        __syncthreads();
        bf16* dst = (pass ? U2T : abT) + (size_t)b * FD * NN;
        #pragma unroll
        for (int it = 0; it < 2; it++) {
            int c = tid + it * 256;
            int r = c >> 3, chunk = c & 7;
            bf16x8 v = *(const bf16x8*)&Tr[r * 72 + chunk * 8];
            *(bf16x8*)&dst[(size_t)(bn + r) * NN + n0 + chunk * 8] = v;
        }
    }
}

// ---------------- K3: m2 split-K.  Gh[h][b][j][k] = sum_{n in half h} U2T[b][j][n]*abT[b][k][n] ----------------
__global__ __launch_bounds__(256, 4)
void m2_mfma(const bf16* __restrict__ U2T, const bf16* __restrict__ abT, float* __restrict__ G)
{
    // LDS: As[2][64][72] + Bs[2][64][72] = 36864 B
    __shared__ __align__(16) bf16 smem[18432];
    typedef bf16 TileM[64][72];
    TileM* As = (TileM*)smem;
    TileM* Bs = (TileM*)(smem + 9216);

    const int tid = threadIdx.x;
    const int wave = tid >> 6, lane = tid & 63;
    const int q = lane >> 4, l16 = lane & 15;
    const int wj = wave >> 1, wk = wave & 1;
    const int b = blockIdx.z >> 1, h = blockIdx.z & 1;
    const int bj = blockIdx.y * 64, bk = blockIdx.x * 64;
    const int r0 = tid >> 3, r1 = r0 + 32, k8 = (tid & 7) * 8;   // 64 rows x 64 cols, 2 rows/thread

    const bf16* Abase = U2T + (size_t)b * FD * NN + (size_t)h * 512;
    const bf16* Bbase = abT + (size_t)b * FD * NN + (size_t)h * 512;
    const bf16* Arow0 = Abase + (size_t)(bj + r0) * NN + k8;
    const bf16* Arow1 = Abase + (size_t)(bj + r1) * NN + k8;
    const bf16* Brow0 = Bbase + (size_t)(bk + r0) * NN + k8;
    const bf16* Brow1 = Bbase + (size_t)(bk + r1) * NN + k8;

    int4 ra0, ra1, rb0, rb1;
#define M2_LOAD(NO) do { \
        ra0 = *(const int4*)&Arow0[NO]; ra1 = *(const int4*)&Arow1[NO]; \
        rb0 = *(const int4*)&Brow0[NO]; rb1 = *(const int4*)&Brow1[NO]; \
    } while (0)
#define M2_STORE(BUF) do { \
        *(int4*)&As[BUF][r0][k8] = ra0; *(int4*)&As[BUF][r1][k8] = ra1; \
        *(int4*)&Bs[BUF][r0][k8] = rb0; *(int4*)&Bs[BUF][r1][k8] = rb1; \
    } while (0)

    floatx4 acc[2][2] = {};
    M2_LOAD(0);
    M2_STORE(0);
    M2_LOAD(64);
    __syncthreads();

    #pragma unroll
    for (int it = 0; it < 8; it++) {
        const int cur = it & 1;
        if (it + 1 < 8) M2_STORE(cur ^ 1);
        if (it + 2 < 8) M2_LOAD((it + 2) * 64);
        #pragma unroll
        for (int kk = 0; kk < 2; kk++) {
            bf16x8 af[2], bq[2];
            #pragma unroll
            for (int mi = 0; mi < 2; mi++)
                af[mi] = *(const bf16x8*)&As[cur][wj * 32 + mi * 16 + l16][kk * 32 + q * 8];
            #pragma unroll
            for (int kj = 0; kj < 2; kj++)
                bq[kj] = *(const bf16x8*)&Bs[cur][wk * 32 + kj * 16 + l16][kk * 32 + q * 8];
            #pragma unroll
            for (int mi = 0; mi < 2; mi++)
                #pragma unroll
                for (int kj = 0; kj < 2; kj++)
                    acc[mi][kj] = __builtin_amdgcn_mfma_f32_16x16x32_bf16(af[mi], bq[kj], acc[mi][kj], 0, 0, 0);
        }
        __syncthreads();
    }
#undef M2_LOAD
#undef M2_STORE

    // direct fp32 stores (no repack, no epilogue syncs)
    float* Gb = G + (size_t)h * GH + (size_t)b * FD * FD;
    #pragma unroll
    for (int mi = 0; mi < 2; mi++)
        #pragma unroll
        for (int i = 0; i < 4; i++) {
            int j = wj * 32 + mi * 16 + q * 4 + i;
            #pragma unroll
            for (int kj = 0; kj < 2; kj++) {
                int k = wk * 32 + kj * 16 + l16;
                Gb[(size_t)(bj + j) * FD + bk + k] = acc[mi][kj][i];
            }
        }
}

// ---------------- K4: out = (x_bf @ G[b]^T(NT) - d*U2)/N + x  (BM=64, dbuf, G = G0+G1) ----------------
__global__ __launch_bounds__(256, 4)
void final_mfma(const float* __restrict__ x, const float* __restrict__ G,
                const float* __restrict__ dpart, const bf16* __restrict__ U2,
                float* __restrict__ out)
{
    // LDS: As[2][64][36] + Bs[2][64][36] = 18432 B
    __shared__ __align__(16) bf16 smem[9216];
    typedef bf16 TileA[64][36];
    TileA* As = (TileA*)smem;
    TileA* Bs = (TileA*)(smem + 4608);

    const int tid = threadIdx.x;
    const int wave = tid >> 6, lane = tid & 63;
    const int q = lane >> 4, l16 = lane & 15;
    const int bm = blockIdx.y * 64, bn = blockIdx.x * 64;
    const float* Gb = G + (size_t)(bm >> 10) * FD * FD;

    const int row = tid >> 2, k8 = (tid & 3) * 8;

    bf16x8 ra, rb;
#define FIN_LOAD(KK) do { \
        const float* s0 = &x[(size_t)(bm + row) * FD + (KK) + k8]; \
        ra = cvt8(*(const float4*)s0, *(const float4*)(s0 + 4)); \
        const float* g0 = &Gb[(size_t)(bn + row) * FD + (KK) + k8]; \
        float4 p0 = *(const float4*)g0, p1 = *(const float4*)(g0 + 4); \
        float4 q0 = *(const float4*)(g0 + GH), q1 = *(const float4*)(g0 + GH + 4); \
        float4 u = { p0.x + q0.x, p0.y + q0.y, p0.z + q0.z, p0.w + q0.w }; \
        float4 v = { p1.x + q1.x, p1.y + q1.y, p1.z + q1.z, p1.w + q1.w }; \
        rb = cvt8(u, v); \
    } while (0)
#define FIN_STORE(BUF) do { \
        *(bf16x8*)&As[BUF][row][k8] = ra; \
        *(bf16x8*)&Bs[BUF][row][k8] = rb; \
    } while (0)

    floatx4 acc[4] = {};
    FIN_LOAD(0);
    FIN_STORE(0);
    FIN_LOAD(32);
    __syncthreads();

    #pragma unroll
    for (int it = 0; it < 8; it++) {
        const int cur = it & 1;
        if (it + 1 < 8) FIN_STORE(cur ^ 1);
        if (it + 2 < 8) FIN_LOAD((it + 2) * 32);
        bf16x8 af = *(const bf16x8*)&As[cur][wave * 16 + l16][q * 8];
        #pragma unroll
        for (int nj = 0; nj < 4; nj++) {
            bf16x8 bq = *(const bf16x8*)&Bs[cur][nj * 16 + l16][q * 8];
            acc[nj] = __builtin_amdgcn_mfma_f32_16x16x32_bf16(af, bq, acc[nj], 0, 0, 0);
        }
        __syncthreads();
    }
#undef FIN_LOAD
#undef FIN_STORE

    #pragma unroll
    for (int i = 0; i < 4; i++) {
        int m = bm + wave * 16 + q * 4 + i;
        float d = dpart[m] + dpart[RR + m] + dpart[2 * RR + m] + dpart[3 * RR + m];
        #pragma unroll
        for (int nj = 0; nj < 4; nj++) {
            int n = bn + nj * 16 + l16;
            float v = (acc[nj][i] - d * (float)U2[(size_t)m * FD + n]) * (1.0f / 1024.0f);
            out[(size_t)m * FD + n] = v + x[(size_t)m * FD + n];
        }
    }
}

extern "C" void kernel_launch(void* const* d_in, const int* in_sizes, int n_in,
                              void* d_out, int out_size, void* d_ws, size_t ws_size,
                              hipStream_t stream)
{
    const float* x  = (const float*)d_in[0];
    const float* Wa = (const float*)d_in[1];
    const float* Wb = (const float*)d_in[2];
    const float* Wu = (const float*)d_in[3];
    const float* bu = (const float*)d_in[4];
    const float* Wr = (const float*)d_in[5];
    float* out = (float*)d_out;

    char* w = (char*)d_ws;
    bf16* Wcb   = (bf16*)w;  w += (size_t)FD * FD * 2;
    bf16* Wab   = (bf16*)w;  w += (size_t)FD * FD * 2;
    float* bc   = (float*)w; w += (size_t)FD * 4;
    bf16* U2    = (bf16*)w;  w += (size_t)RR * FD * 2;
    bf16* abT   = (bf16*)w;  w += (size_t)RR * FD * 2;
    bf16* U2T   = (bf16*)w;  w += (size_t)RR * FD * 2;
    float* G    = (float*)w; w += (size_t)2 * GH * 4;   // two split-K halves, fp32
    float* dpart= (float*)w; w += (size_t)4 * RR * 4;

    dim3 blk(256);

    prep<<<dim3(513), blk, 0, stream>>>(Wa, Wb, Wu, bu, Wr, Wcb, Wab, bc);

    proj<<<dim3(4, 256), blk, 0, stream>>>(x, Wab, Wcb, U2, abT, U2T, bc, dpart);

    m2_mfma<<<dim3(4, 4, 32), blk, 0, stream>>>(U2T, abT, G);

    final_mfma<<<dim3(4, 256), blk, 0, stream>>>(x, G, dpart, U2, out);
}